// Round 5
// baseline (261.239 us; speedup 1.0000x reference)
//
#include <hip/hip_runtime.h>
#include <stdint.h>

#define EPS 1e-5f

typedef float f32x4 __attribute__((ext_vector_type(4)));
typedef float f32x16 __attribute__((ext_vector_type(16)));
typedef __bf16 bf16x8 __attribute__((ext_vector_type(8)));
typedef uint32_t u32x4 __attribute__((ext_vector_type(4)));

__device__ __forceinline__ ushort f2bf(float f){
  union { float f; uint32_t u; } v; v.f = f;
  uint32_t r = v.u + 0x7fffu + ((v.u >> 16) & 1u);
  return (ushort)(r >> 16);
}

__device__ __forceinline__ float bf2f(ushort u){
  union { uint32_t u; float f; } v; v.u = ((uint32_t)u) << 16;
  return v.f;
}

__device__ __forceinline__ uint32_t pk2bf(float a, float b){
  __bf16 x = (__bf16)a, y = (__bf16)b;
  return (uint32_t)__builtin_bit_cast(ushort, x) |
         ((uint32_t)__builtin_bit_cast(ushort, y) << 16);
}

__device__ __forceinline__ f32x4 mfma16(bf16x8 a, bf16x8 b, f32x4 c){
  return __builtin_amdgcn_mfma_f32_16x16x32_bf16(a, b, c, 0, 0, 0);
}
__device__ __forceinline__ f32x16 mfma32(bf16x8 a, bf16x8 b, f32x16 c){
  return __builtin_amdgcn_mfma_f32_32x32x16_bf16(a, b, c, 0, 0, 0);
}

// ---------------- fused: weight cast + groupnorm stats stage 1 ----------------
// grid 1792: [0,768) weight cast, [768,1792) gn partial sums
__global__ __launch_bounds__(256) void k_pg(const float* wq, const float* wp, const float* x,
                                            ushort* wqb, ushort* wpb, float2* part){
  __shared__ float red[8];
  int bid = blockIdx.x;
  if (bid < 768){
    int i = bid * 256 + threadIdx.x;
    if (i < 3*256*256) wqb[i] = f2bf(wq[i]);
    if (i < 256*256)   wpb[i] = f2bf(wp[i]);
    return;
  }
  int gb = bid - 768;
  int bg = gb >> 6, pb = gb & 63;
  const f32x4* base = (const f32x4*)(x + (size_t)bg*131072 + (size_t)pb*2048);
  float s = 0.f, ss = 0.f;
  #pragma unroll
  for (int it = 0; it < 2; ++it){
    f32x4 v = base[threadIdx.x + it*256];
    #pragma unroll
    for (int j = 0; j < 4; ++j){ s += v[j]; ss += v[j]*v[j]; }
  }
  #pragma unroll
  for (int off = 1; off < 64; off <<= 1){
    s  += __shfl_xor(s,  off);
    ss += __shfl_xor(ss, off);
  }
  int wid = threadIdx.x >> 6;
  if ((threadIdx.x & 63) == 0){ red[wid] = s; red[4 + wid] = ss; }
  __syncthreads();
  if (threadIdx.x == 0){
    part[gb] = make_float2(red[0]+red[1]+red[2]+red[3],
                           red[4]+red[5]+red[6]+red[7]);
  }
}

// ---------------- fused GN finish + normalize + QKV GEMM ----------------
// grid (128 nt-of-32, 2 b) x 512; writes Qb/Kb [bh][n][d], Vb [bh][d][n]
__global__ __launch_bounds__(512) void k_nqkv(const float* x, const float* gamma, const float* beta,
                                              const float2* part, const ushort* wqb, const float* bqkv,
                                              ushort* Qb, ushort* Kb, ushort* Vb){
  __shared__ ushort A[32][264];    // [n][c]
  __shared__ ushort Cl[32][136];   // [n][o_local]
  __shared__ float2 st[8];
  int nt = blockIdx.x, b = blockIdx.y;
  int t = threadIdx.x, lane = t & 63, wid = t >> 6;

  // finish GN stats (8 waves x 8 groups)
  {
    float2 p = part[(b*8 + wid)*64 + lane];
    float s = p.x, ss = p.y;
    #pragma unroll
    for (int off = 1; off < 64; off <<= 1){
      s  += __shfl_xor(s,  off);
      ss += __shfl_xor(ss, off);
    }
    if (lane == 0){
      const float inv = 1.f / 131072.f;
      float mean = s * inv;
      float var  = ss * inv - mean*mean;
      st[wid] = make_float2(mean, rsqrtf(var + EPS));
    }
  }
  __syncthreads();

  // normalize x-tile [256c x 32n] -> A[n][c] bf16
  {
    int c = t >> 1, nh = t & 1;
    float2 s0 = st[c >> 5];
    float g  = gamma[c] * s0.y;
    float bt = beta[c] - s0.x * g;
    const float* xr = x + ((size_t)(b*256 + c))*4096 + nt*32 + nh*16;
    #pragma unroll
    for (int j4 = 0; j4 < 4; ++j4){
      f32x4 v = *(const f32x4*)(xr + j4*4);
      #pragma unroll
      for (int e = 0; e < 4; ++e) A[nh*16 + j4*4 + e][c] = f2bf(v[e]*g + bt);
    }
  }
  __syncthreads();

  // GEMM: C[32n x 768o] = A x W^T
  int l15 = lane & 15, g4 = lane >> 4;
  f32x4 acc[6][2];
  #pragma unroll
  for (int of = 0; of < 6; ++of)
    #pragma unroll
    for (int mf = 0; mf < 2; ++mf) acc[of][mf] = (f32x4){0.f,0.f,0.f,0.f};

  #pragma unroll
  for (int ks = 0; ks < 8; ++ks){
    bf16x8 a0 = *(const bf16x8*)&A[l15][ks*32 + g4*8];
    bf16x8 a1 = *(const bf16x8*)&A[16 + l15][ks*32 + g4*8];
    #pragma unroll
    for (int of = 0; of < 6; ++of){
      int o = of*128 + wid*16 + l15;
      bf16x8 bw = *(const bf16x8*)(wqb + (size_t)o*256 + ks*32 + g4*8);
      acc[of][0] = mfma16(a0, bw, acc[of][0]);
      acc[of][1] = mfma16(a1, bw, acc[of][1]);
    }
  }

  // epilogue: per 128-o slab, stage in LDS, coalesced writeout
  #pragma unroll
  for (int of = 0; of < 6; ++of){
    __syncthreads();
    int o = of*128 + wid*16 + l15;
    float bias = bqkv[o];
    #pragma unroll
    for (int mf = 0; mf < 2; ++mf)
      #pragma unroll
      for (int r = 0; r < 4; ++r)
        Cl[mf*16 + g4*4 + r][wid*16 + l15] = f2bf(acc[of][mf][r] + bias);
    __syncthreads();
    if (of < 4){
      // Q or K: [bh][n][d]
      ushort* basep = (of < 2) ? Qb : Kb;
      int nl = t >> 4, oc = (t & 15) * 8;
      int h = (of & 1)*2 + (oc >> 6), d0 = oc & 63;
      ushort* dst = basep + (((size_t)(b*4 + h))*4096 + nt*32 + nl)*64 + d0;
      *(uint4*)dst = *(uint4*)&Cl[nl][oc];
    } else {
      // V: [bh][d][n]
      int dl = t >> 2, nc = (t & 3) * 8;
      int h = (of - 4)*2 + (dl >> 6), d = dl & 63;
      uint32_t pk[4];
      #pragma unroll
      for (int j = 0; j < 4; ++j){
        uint32_t lo = Cl[nc + 2*j][dl], hiu = Cl[nc + 2*j + 1][dl];
        pk[j] = lo | (hiu << 16);
      }
      ushort* dst = Vb + (((size_t)(b*4 + h))*64 + d)*4096 + nt*32 + nc;
      *(uint4*)dst = make_uint4(pk[0], pk[1], pk[2], pk[3]);
    }
  }
}

// ---------------- flash attention: 32q/wave, zero LDS/barriers, split-KV ----------------
// grid 8*32*SPLIT blocks x 256 (4 waves, each one 32-q tile); bh = blockIdx&7 (XCD-local)
template<int SPLIT>
__global__ __launch_bounds__(256, 4) void k_attn(const ushort* Qb, const ushort* Kb,
                                                 const ushort* Vb, ushort* Opart, float2* ML){
  const float SCL2 = 0.125f * 1.44269504f;   // scale * log2(e)
  int bh = blockIdx.x & 7;
  int within = blockIdx.x >> 3;              // [0, 32*SPLIT)
  int sp = within >> 5, qb = within & 31;
  int t = threadIdx.x, wid = t >> 6, l = t & 63, l31 = l & 31, hi = l >> 5;
  int qt = qb*4 + wid;                       // 32-row q tile index [0,128)

  const ushort* Qg = Qb + (size_t)bh*262144;
  const ushort* Kg = Kb + (size_t)bh*262144;
  const ushort* Vg = Vb + (size_t)bh*262144;

  // Q frags [dsub]
  bf16x8 qf[4];
  #pragma unroll
  for (int dsub = 0; dsub < 4; ++dsub)
    qf[dsub] = *(const bf16x8*)(Qg + (size_t)(qt*32 + l31)*64 + dsub*16 + hi*8);

  // K A-row permutation: swap bits 2<->3 so S^T lands in P-B-frag layout
  int rowp = (l31 & 19) | ((l31 & 4) << 1) | ((l31 & 8) >> 1);
  const ushort* Kbase = Kg + (size_t)rowp*64 + hi*8;
  const ushort* Vbase = Vg + (size_t)l31*4096 + hi*8;

  f32x16 o[2];   // [dt]  O^T[d][q]
  #pragma unroll
  for (int dt = 0; dt < 2; ++dt)
    #pragma unroll
    for (int r = 0; r < 16; ++r) o[dt][r] = 0.f;
  float m_s = -INFINITY, l_s = 0.f;

  const int kbBeg = sp * (64 / SPLIT), kbEnd = kbBeg + 64 / SPLIT;
  for (int kb = kbBeg; kb < kbEnd; ++kb){
    // K frags [kt][dsub]
    bf16x8 kf[2][4];
    #pragma unroll
    for (int kt = 0; kt < 2; ++kt)
      #pragma unroll
      for (int dsub = 0; dsub < 4; ++dsub)
        kf[kt][dsub] = *(const bf16x8*)(Kbase + (size_t)(kb*64 + kt*32)*64 + dsub*16);

    // V frags [dt][c4] (independent of softmax; loads issue early)
    bf16x8 vf[2][4];
    #pragma unroll
    for (int dt = 0; dt < 2; ++dt)
      #pragma unroll
      for (int c4 = 0; c4 < 4; ++c4)
        vf[dt][c4] = *(const bf16x8*)(Vbase + (size_t)dt*131072 + kb*64 + c4*16);

    // QK: S^T[kv][q]
    f32x16 s[2];
    __builtin_amdgcn_s_setprio(1);
    #pragma unroll
    for (int kt = 0; kt < 2; ++kt){
      f32x16 acc;
      #pragma unroll
      for (int r = 0; r < 16; ++r) acc[r] = 0.f;
      #pragma unroll
      for (int dsub = 0; dsub < 4; ++dsub)
        acc = mfma32(kf[kt][dsub], qf[dsub], acc);
      s[kt] = acc;
    }
    __builtin_amdgcn_s_setprio(0);

    // softmax (q lane-local; only cross-lane partner is l^32)
    f32x16 mx = s[0];
    #pragma unroll
    for (int r = 0; r < 16; ++r) mx[r] = fmaxf(mx[r], s[1][r]);
    #pragma unroll
    for (int off = 8; off > 0; off >>= 1)
      #pragma unroll
      for (int r = 0; r < off; ++r) mx[r] = fmaxf(mx[r], mx[r + off]);
    float vm = fmaxf(mx[0], __shfl_xor(mx[0], 32)) * SCL2;

    if (__any(vm > m_s + 8.f)){
      float mn = fmaxf(m_s, vm);
      float a = __builtin_amdgcn_exp2f(m_s - mn);
      m_s = mn; l_s *= a;
      #pragma unroll
      for (int dt = 0; dt < 2; ++dt)
        #pragma unroll
        for (int r = 0; r < 16; ++r) o[dt][r] *= a;
    }
    {
      float r0 = 0.f, r1 = 0.f, r2 = 0.f, r3 = 0.f;
      #pragma unroll
      for (int kt = 0; kt < 2; ++kt)
        #pragma unroll
        for (int r = 0; r < 16; r += 4){
          float e0 = __builtin_amdgcn_exp2f(__builtin_fmaf(s[kt][r+0], SCL2, -m_s));
          float e1 = __builtin_amdgcn_exp2f(__builtin_fmaf(s[kt][r+1], SCL2, -m_s));
          float e2 = __builtin_amdgcn_exp2f(__builtin_fmaf(s[kt][r+2], SCL2, -m_s));
          float e3 = __builtin_amdgcn_exp2f(__builtin_fmaf(s[kt][r+3], SCL2, -m_s));
          s[kt][r+0] = e0; s[kt][r+1] = e1;
          s[kt][r+2] = e2; s[kt][r+3] = e3;
          r0 += e0; r1 += e1; r2 += e2; r3 += e3;
        }
      float rr = (r0 + r1) + (r2 + r3);
      rr += __shfl_xor(rr, 32);
      l_s += rr;
    }

    // P -> bf16 B-frags (pure in-lane thanks to the row permutation)
    bf16x8 pf[2][2];   // [kt][ks]
    #pragma unroll
    for (int kt = 0; kt < 2; ++kt)
      #pragma unroll
      for (int ks = 0; ks < 2; ++ks){
        u32x4 w;
        #pragma unroll
        for (int c = 0; c < 4; ++c)
          w[c] = pk2bf(s[kt][8*ks + 2*c], s[kt][8*ks + 2*c + 1]);
        pf[kt][ks] = __builtin_bit_cast(bf16x8, w);
      }

    // PV: O^T[d][q]
    __builtin_amdgcn_s_setprio(1);
    #pragma unroll
    for (int dt = 0; dt < 2; ++dt)
      #pragma unroll
      for (int kt = 0; kt < 2; ++kt)
        #pragma unroll
        for (int ks = 0; ks < 2; ++ks)
          o[dt] = mfma32(vf[dt][kt*2 + ks], pf[kt][ks], o[dt]);
    __builtin_amdgcn_s_setprio(0);
  }

  // epilogue: raw partial O [pw][32n][64d] + (m,l)
  int pw = (bh*SPLIT + sp)*128 + qt;
  if (hi == 0) ML[(size_t)pw*32 + l31] = make_float2(m_s, l_s);
  ushort* dst = Opart + (size_t)pw*2048;
  #pragma unroll
  for (int dt = 0; dt < 2; ++dt)
    #pragma unroll
    for (int rq = 0; rq < 4; ++rq){
      int d0 = dt*32 + rq*8 + 4*hi;
      uint2 w = make_uint2(pk2bf(o[dt][rq*4+0], o[dt][rq*4+1]),
                           pk2bf(o[dt][rq*4+2], o[dt][rq*4+3]));
      *(uint2*)(dst + (size_t)l31*64 + d0) = w;
    }
}

// ---------------- fused combine + proj GEMM + bias + residual ----------------
// grid (64 nt, 2 b) x 512; combines split partials into LDS A[64n][256ci], then GEMM
template<int SPLIT>
__global__ __launch_bounds__(512) void k_cproj(const ushort* Opart, const float2* ML,
                                               const ushort* wpb, const float* bproj,
                                               const float* x, float* out){
  __shared__ ushort A[64][264];
  int nt = blockIdx.x, b = blockIdx.y;
  int t = threadIdx.x;

  // combine phase: t -> (n_local = t>>3, d0 = (t&7)*8); loop heads
  int n_local = t >> 3, d0 = (t & 7) * 8;
  int tile = n_local >> 5, ql = n_local & 31;
  int qt32 = nt*2 + tile;
  #pragma unroll
  for (int h = 0; h < 4; ++h){
    int bh = b*4 + h;
    float2 mls[SPLIT];
    float m = -INFINITY;
    #pragma unroll
    for (int sp = 0; sp < SPLIT; ++sp){
      mls[sp] = ML[((size_t)((bh*SPLIT + sp)*128 + qt32))*32 + ql];
      m = fmaxf(m, mls[sp].x);
    }
    float den = 0.f, w[SPLIT];
    #pragma unroll
    for (int sp = 0; sp < SPLIT; ++sp){
      w[sp] = __builtin_amdgcn_exp2f(mls[sp].x - m);
      den += mls[sp].y * w[sp];
    }
    float inv = 1.f / den;
    float vals[8];
    #pragma unroll
    for (int j = 0; j < 8; ++j) vals[j] = 0.f;
    #pragma unroll
    for (int sp = 0; sp < SPLIT; ++sp){
      const ushort* src = Opart + ((size_t)((bh*SPLIT + sp)*128 + qt32))*2048 + (size_t)ql*64 + d0;
      uint4 a0 = *(const uint4*)src;
      float f = w[sp] * inv;
      #pragma unroll
      for (int j = 0; j < 8; ++j) vals[j] += bf2f(((const ushort*)&a0)[j]) * f;
    }
    uint32_t pk[4];
    #pragma unroll
    for (int j = 0; j < 4; ++j) pk[j] = pk2bf(vals[2*j], vals[2*j+1]);
    *(uint4*)&A[n_local][h*64 + d0] = make_uint4(pk[0], pk[1], pk[2], pk[3]);
  }
  __syncthreads();

  // GEMM phase: out[b][o][n] = W[o][ci] * A[n][ci]^T + bias + residual
  int lane = t & 63, wid = t >> 6, l15 = lane & 15, g4 = lane >> 4;
  f32x4 acc[4][2];
  #pragma unroll
  for (int mf = 0; mf < 4; ++mf)
    #pragma unroll
    for (int of = 0; of < 2; ++of) acc[mf][of] = (f32x4){0.f,0.f,0.f,0.f};

  #pragma unroll
  for (int ks = 0; ks < 8; ++ks){
    bf16x8 aa[4];
    #pragma unroll
    for (int mf = 0; mf < 4; ++mf)
      aa[mf] = *(const bf16x8*)&A[mf*16 + l15][ks*32 + g4*8];
    #pragma unroll
    for (int of = 0; of < 2; ++of){
      int o = of*128 + wid*16 + l15;
      bf16x8 bw = *(const bf16x8*)(wpb + (size_t)o*256 + ks*32 + g4*8);
      #pragma unroll
      for (int mf = 0; mf < 4; ++mf)
        acc[mf][of] = mfma16(aa[mf], bw, acc[mf][of]);
    }
  }

  #pragma unroll
  for (int of = 0; of < 2; ++of){
    int o = of*128 + wid*16 + l15;
    float bias = bproj[o];
    size_t cbase = ((size_t)b*256 + o)*4096;
    #pragma unroll
    for (int mf = 0; mf < 4; ++mf){
      int n0 = nt*64 + mf*16 + g4*4;
      f32x4 res = *(const f32x4*)(x + cbase + n0);
      f32x4 ov;
      #pragma unroll
      for (int r = 0; r < 4; ++r) ov[r] = acc[mf][of][r] + bias + res[r];
      *(f32x4*)(out + cbase + n0) = ov;
    }
  }
}

extern "C" void kernel_launch(void* const* d_in, const int* in_sizes, int n_in,
                              void* d_out, int out_size, void* d_ws, size_t ws_size,
                              hipStream_t stream) {
  const float* x     = (const float*)d_in[0];
  const float* gamma = (const float*)d_in[1];
  const float* beta  = (const float*)d_in[2];
  const float* wqkv  = (const float*)d_in[3];
  const float* bqkv  = (const float*)d_in[4];
  const float* wproj = (const float*)d_in[5];
  const float* bproj = (const float*)d_in[6];
  float* out = (float*)d_out;

  const size_t MiB = 1024*1024;
  char* ws = (char*)d_ws;
  float2* part   = (float2*)(ws + 0);            // 8 KB
  ushort* wq_b   = (ushort*)(ws + 16384);        // 384 KB
  ushort* wp_b   = (ushort*)(ws + 409600);       // 128 KB
  ushort* Qb     = (ushort*)(ws + 1*MiB);        // 4 MiB  [bh][n][d]
  ushort* Kb     = (ushort*)(ws + 5*MiB);        // 4 MiB  [bh][n][d]
  ushort* Vb     = (ushort*)(ws + 9*MiB);        // 4 MiB  [bh][d][n]
  ushort* Opart  = (ushort*)(ws + 13*MiB);       // 4*SPLIT MiB  [pw][32n][64d]

  int split = (ws_size >= 31*MiB) ? 4 : 2;
  float2* ML = (float2*)(ws + (13 + 4*(size_t)split)*MiB);  // 0.25*SPLIT MiB

  k_pg  <<<1792, 256, 0, stream>>>(wqkv, wproj, x, wq_b, wp_b, part);
  k_nqkv<<<dim3(128,2), 512, 0, stream>>>(x, gamma, beta, part, wq_b, bqkv, Qb, Kb, Vb);
  if (split == 4){
    k_attn<4><<<1024, 256, 0, stream>>>(Qb, Kb, Vb, Opart, ML);
    k_cproj<4><<<dim3(64,2), 512, 0, stream>>>(Opart, ML, wp_b, bproj, x, out);
  } else {
    k_attn<2><<<512, 256, 0, stream>>>(Qb, Kb, Vb, Opart, ML);
    k_cproj<2><<<dim3(64,2), 512, 0, stream>>>(Opart, ML, wp_b, bproj, x, out);
  }
}

// Round 6
// 223.361 us; speedup vs baseline: 1.1696x; 1.1696x over previous
//
#include <hip/hip_runtime.h>
#include <stdint.h>

#define EPS 1e-5f

typedef float f32x4 __attribute__((ext_vector_type(4)));
typedef float f32x16 __attribute__((ext_vector_type(16)));
typedef __bf16 bf16x8 __attribute__((ext_vector_type(8)));
typedef uint32_t u32x4 __attribute__((ext_vector_type(4)));

__device__ __forceinline__ ushort f2bf(float f){
  union { float f; uint32_t u; } v; v.f = f;
  uint32_t r = v.u + 0x7fffu + ((v.u >> 16) & 1u);
  return (ushort)(r >> 16);
}

__device__ __forceinline__ float bf2f(ushort u){
  union { uint32_t u; float f; } v; v.u = ((uint32_t)u) << 16;
  return v.f;
}

__device__ __forceinline__ uint32_t pk2bf(float a, float b){
  __bf16 x = (__bf16)a, y = (__bf16)b;
  return (uint32_t)__builtin_bit_cast(ushort, x) |
         ((uint32_t)__builtin_bit_cast(ushort, y) << 16);
}

__device__ __forceinline__ f32x4 mfma16(bf16x8 a, bf16x8 b, f32x4 c){
  return __builtin_amdgcn_mfma_f32_16x16x32_bf16(a, b, c, 0, 0, 0);
}
__device__ __forceinline__ f32x16 mfma32(bf16x8 a, bf16x8 b, f32x16 c){
  return __builtin_amdgcn_mfma_f32_32x32x16_bf16(a, b, c, 0, 0, 0);
}

// ---------------- fused: weight cast + groupnorm stats stage 1 ----------------
// grid 1792: [0,768) weight cast, [768,1792) gn partial sums
__global__ __launch_bounds__(256) void k_pg(const float* wq, const float* wp, const float* x,
                                            ushort* wqb, ushort* wpb, float2* part){
  __shared__ float red[8];
  int bid = blockIdx.x;
  if (bid < 768){
    int i = bid * 256 + threadIdx.x;
    if (i < 3*256*256) wqb[i] = f2bf(wq[i]);
    if (i < 256*256)   wpb[i] = f2bf(wp[i]);
    return;
  }
  int gb = bid - 768;
  int bg = gb >> 6, pb = gb & 63;
  const f32x4* base = (const f32x4*)(x + (size_t)bg*131072 + (size_t)pb*2048);
  float s = 0.f, ss = 0.f;
  #pragma unroll
  for (int it = 0; it < 2; ++it){
    f32x4 v = base[threadIdx.x + it*256];
    #pragma unroll
    for (int j = 0; j < 4; ++j){ s += v[j]; ss += v[j]*v[j]; }
  }
  #pragma unroll
  for (int off = 1; off < 64; off <<= 1){
    s  += __shfl_xor(s,  off);
    ss += __shfl_xor(ss, off);
  }
  int wid = threadIdx.x >> 6;
  if ((threadIdx.x & 63) == 0){ red[wid] = s; red[4 + wid] = ss; }
  __syncthreads();
  if (threadIdx.x == 0){
    part[gb] = make_float2(red[0]+red[1]+red[2]+red[3],
                           red[4]+red[5]+red[6]+red[7]);
  }
}

// ---------------- fused GN finish + normalize + QKV GEMM ----------------
// grid (128 nt-of-32, 2 b) x 512; writes Qb/Kb [bh][n][d], Vb [bh][d][n]
__global__ __launch_bounds__(512) void k_nqkv(const float* x, const float* gamma, const float* beta,
                                              const float2* part, const ushort* wqb, const float* bqkv,
                                              ushort* Qb, ushort* Kb, ushort* Vb){
  __shared__ ushort A[32][264];    // [n][c]
  __shared__ ushort Cl[32][136];   // [n][o_local]
  __shared__ float2 st[8];
  int nt = blockIdx.x, b = blockIdx.y;
  int t = threadIdx.x, lane = t & 63, wid = t >> 6;

  // finish GN stats (8 waves x 8 groups)
  {
    float2 p = part[(b*8 + wid)*64 + lane];
    float s = p.x, ss = p.y;
    #pragma unroll
    for (int off = 1; off < 64; off <<= 1){
      s  += __shfl_xor(s,  off);
      ss += __shfl_xor(ss, off);
    }
    if (lane == 0){
      const float inv = 1.f / 131072.f;
      float mean = s * inv;
      float var  = ss * inv - mean*mean;
      st[wid] = make_float2(mean, rsqrtf(var + EPS));
    }
  }
  __syncthreads();

  // normalize x-tile [256c x 32n] -> A[n][c] bf16
  {
    int c = t >> 1, nh = t & 1;
    float2 s0 = st[c >> 5];
    float g  = gamma[c] * s0.y;
    float bt = beta[c] - s0.x * g;
    const float* xr = x + ((size_t)(b*256 + c))*4096 + nt*32 + nh*16;
    #pragma unroll
    for (int j4 = 0; j4 < 4; ++j4){
      f32x4 v = *(const f32x4*)(xr + j4*4);
      #pragma unroll
      for (int e = 0; e < 4; ++e) A[nh*16 + j4*4 + e][c] = f2bf(v[e]*g + bt);
    }
  }
  __syncthreads();

  // GEMM: C[32n x 768o] = A x W^T
  int l15 = lane & 15, g4 = lane >> 4;
  f32x4 acc[6][2];
  #pragma unroll
  for (int of = 0; of < 6; ++of)
    #pragma unroll
    for (int mf = 0; mf < 2; ++mf) acc[of][mf] = (f32x4){0.f,0.f,0.f,0.f};

  #pragma unroll
  for (int ks = 0; ks < 8; ++ks){
    bf16x8 a0 = *(const bf16x8*)&A[l15][ks*32 + g4*8];
    bf16x8 a1 = *(const bf16x8*)&A[16 + l15][ks*32 + g4*8];
    #pragma unroll
    for (int of = 0; of < 6; ++of){
      int o = of*128 + wid*16 + l15;
      bf16x8 bw = *(const bf16x8*)(wqb + (size_t)o*256 + ks*32 + g4*8);
      acc[of][0] = mfma16(a0, bw, acc[of][0]);
      acc[of][1] = mfma16(a1, bw, acc[of][1]);
    }
  }

  // epilogue: per 128-o slab, stage in LDS, coalesced writeout
  #pragma unroll
  for (int of = 0; of < 6; ++of){
    __syncthreads();
    int o = of*128 + wid*16 + l15;
    float bias = bqkv[o];
    #pragma unroll
    for (int mf = 0; mf < 2; ++mf)
      #pragma unroll
      for (int r = 0; r < 4; ++r)
        Cl[mf*16 + g4*4 + r][wid*16 + l15] = f2bf(acc[of][mf][r] + bias);
    __syncthreads();
    if (of < 4){
      // Q or K: [bh][n][d]
      ushort* basep = (of < 2) ? Qb : Kb;
      int nl = t >> 4, oc = (t & 15) * 8;
      int h = (of & 1)*2 + (oc >> 6), d0 = oc & 63;
      ushort* dst = basep + (((size_t)(b*4 + h))*4096 + nt*32 + nl)*64 + d0;
      *(uint4*)dst = *(uint4*)&Cl[nl][oc];
    } else {
      // V: [bh][d][n]
      int dl = t >> 2, nc = (t & 3) * 8;
      int h = (of - 4)*2 + (dl >> 6), d = dl & 63;
      uint32_t pk[4];
      #pragma unroll
      for (int j = 0; j < 4; ++j){
        uint32_t lo = Cl[nc + 2*j][dl], hiu = Cl[nc + 2*j + 1][dl];
        pk[j] = lo | (hiu << 16);
      }
      ushort* dst = Vb + (((size_t)(b*4 + h))*64 + d)*4096 + nt*32 + nc;
      *(uint4*)dst = make_uint4(pk[0], pk[1], pk[2], pk[3]);
    }
  }
}

// ---------------- flash attention: 32q/wave, zero LDS/barriers, split-KV ----------------
// grid 8*32*SPLIT blocks x 256 (4 waves, each one 32-q tile); bh = blockIdx&7 (XCD-local)
// NOTE: __launch_bounds__(256,3) — (256,4) caps VGPR at 128 and forces scratch
// spills (R5: 210MB writeback traffic, 2.3x regression). 3/EU = 170 VGPR, no spill.
template<int SPLIT>
__global__ __launch_bounds__(256, 3) void k_attn(const ushort* Qb, const ushort* Kb,
                                                 const ushort* Vb, ushort* Opart, float2* ML){
  const float SCL2 = 0.125f * 1.44269504f;   // scale * log2(e)
  int bh = blockIdx.x & 7;
  int within = blockIdx.x >> 3;              // [0, 32*SPLIT)
  int sp = within >> 5, qb = within & 31;
  int t = threadIdx.x, wid = t >> 6, l = t & 63, l31 = l & 31, hi = l >> 5;
  int qt = qb*4 + wid;                       // 32-row q tile index [0,128)

  const ushort* Qg = Qb + (size_t)bh*262144;
  const ushort* Kg = Kb + (size_t)bh*262144;
  const ushort* Vg = Vb + (size_t)bh*262144;

  // Q frags [dsub]
  bf16x8 qf[4];
  #pragma unroll
  for (int dsub = 0; dsub < 4; ++dsub)
    qf[dsub] = *(const bf16x8*)(Qg + (size_t)(qt*32 + l31)*64 + dsub*16 + hi*8);

  // K A-row permutation: swap bits 2<->3 so S^T lands in P-B-frag layout
  int rowp = (l31 & 19) | ((l31 & 4) << 1) | ((l31 & 8) >> 1);
  const ushort* Kbase = Kg + (size_t)rowp*64 + hi*8;
  const ushort* Vbase = Vg + (size_t)l31*4096 + hi*8;

  f32x16 o[2];   // [dt]  O^T[d][q]
  #pragma unroll
  for (int dt = 0; dt < 2; ++dt)
    #pragma unroll
    for (int r = 0; r < 16; ++r) o[dt][r] = 0.f;
  float m_s = -INFINITY, l_s = 0.f;

  const int kbBeg = sp * (64 / SPLIT), kbEnd = kbBeg + 64 / SPLIT;
  for (int kb = kbBeg; kb < kbEnd; ++kb){
    // K frags [kt][dsub]
    bf16x8 kf[2][4];
    #pragma unroll
    for (int kt = 0; kt < 2; ++kt)
      #pragma unroll
      for (int dsub = 0; dsub < 4; ++dsub)
        kf[kt][dsub] = *(const bf16x8*)(Kbase + (size_t)(kb*64 + kt*32)*64 + dsub*16);

    // V frags [dt][c4] (independent of softmax; loads issue early)
    bf16x8 vf[2][4];
    #pragma unroll
    for (int dt = 0; dt < 2; ++dt)
      #pragma unroll
      for (int c4 = 0; c4 < 4; ++c4)
        vf[dt][c4] = *(const bf16x8*)(Vbase + (size_t)dt*131072 + kb*64 + c4*16);

    // QK: S^T[kv][q]
    f32x16 s[2];
    __builtin_amdgcn_s_setprio(1);
    #pragma unroll
    for (int kt = 0; kt < 2; ++kt){
      f32x16 acc;
      #pragma unroll
      for (int r = 0; r < 16; ++r) acc[r] = 0.f;
      #pragma unroll
      for (int dsub = 0; dsub < 4; ++dsub)
        acc = mfma32(kf[kt][dsub], qf[dsub], acc);
      s[kt] = acc;
    }
    __builtin_amdgcn_s_setprio(0);

    // softmax (q lane-local; only cross-lane partner is l^32)
    f32x16 mx = s[0];
    #pragma unroll
    for (int r = 0; r < 16; ++r) mx[r] = fmaxf(mx[r], s[1][r]);
    #pragma unroll
    for (int off = 8; off > 0; off >>= 1)
      #pragma unroll
      for (int r = 0; r < off; ++r) mx[r] = fmaxf(mx[r], mx[r + off]);
    float vm = fmaxf(mx[0], __shfl_xor(mx[0], 32)) * SCL2;

    if (__any(vm > m_s + 8.f)){
      float mn = fmaxf(m_s, vm);
      float a = __builtin_amdgcn_exp2f(m_s - mn);
      m_s = mn; l_s *= a;
      #pragma unroll
      for (int dt = 0; dt < 2; ++dt)
        #pragma unroll
        for (int r = 0; r < 16; ++r) o[dt][r] *= a;
    }
    {
      float r0 = 0.f, r1 = 0.f, r2 = 0.f, r3 = 0.f;
      #pragma unroll
      for (int kt = 0; kt < 2; ++kt)
        #pragma unroll
        for (int r = 0; r < 16; r += 4){
          float e0 = __builtin_amdgcn_exp2f(__builtin_fmaf(s[kt][r+0], SCL2, -m_s));
          float e1 = __builtin_amdgcn_exp2f(__builtin_fmaf(s[kt][r+1], SCL2, -m_s));
          float e2 = __builtin_amdgcn_exp2f(__builtin_fmaf(s[kt][r+2], SCL2, -m_s));
          float e3 = __builtin_amdgcn_exp2f(__builtin_fmaf(s[kt][r+3], SCL2, -m_s));
          s[kt][r+0] = e0; s[kt][r+1] = e1;
          s[kt][r+2] = e2; s[kt][r+3] = e3;
          r0 += e0; r1 += e1; r2 += e2; r3 += e3;
        }
      float rr = (r0 + r1) + (r2 + r3);
      rr += __shfl_xor(rr, 32);
      l_s += rr;
    }

    // P -> bf16 B-frags (pure in-lane thanks to the row permutation)
    bf16x8 pf[2][2];   // [kt][ks]
    #pragma unroll
    for (int kt = 0; kt < 2; ++kt)
      #pragma unroll
      for (int ks = 0; ks < 2; ++ks){
        u32x4 w;
        #pragma unroll
        for (int c = 0; c < 4; ++c)
          w[c] = pk2bf(s[kt][8*ks + 2*c], s[kt][8*ks + 2*c + 1]);
        pf[kt][ks] = __builtin_bit_cast(bf16x8, w);
      }

    // PV: O^T[d][q]
    __builtin_amdgcn_s_setprio(1);
    #pragma unroll
    for (int dt = 0; dt < 2; ++dt)
      #pragma unroll
      for (int kt = 0; kt < 2; ++kt)
        #pragma unroll
        for (int ks = 0; ks < 2; ++ks)
          o[dt] = mfma32(vf[dt][kt*2 + ks], pf[kt][ks], o[dt]);
    __builtin_amdgcn_s_setprio(0);
  }

  // epilogue: raw partial O [pw][32n][64d] + (m,l)
  int pw = (bh*SPLIT + sp)*128 + qt;
  if (hi == 0) ML[(size_t)pw*32 + l31] = make_float2(m_s, l_s);
  ushort* dst = Opart + (size_t)pw*2048;
  #pragma unroll
  for (int dt = 0; dt < 2; ++dt)
    #pragma unroll
    for (int rq = 0; rq < 4; ++rq){
      int d0 = dt*32 + rq*8 + 4*hi;
      uint2 w = make_uint2(pk2bf(o[dt][rq*4+0], o[dt][rq*4+1]),
                           pk2bf(o[dt][rq*4+2], o[dt][rq*4+3]));
      *(uint2*)(dst + (size_t)l31*64 + d0) = w;
    }
}

// ---------------- fused combine + proj GEMM + bias + residual ----------------
// grid (64 nt, 2 b) x 512; combines split partials into LDS A[64n][256ci], then GEMM
template<int SPLIT>
__global__ __launch_bounds__(512) void k_cproj(const ushort* Opart, const float2* ML,
                                               const ushort* wpb, const float* bproj,
                                               const float* x, float* out){
  __shared__ ushort A[64][264];
  int nt = blockIdx.x, b = blockIdx.y;
  int t = threadIdx.x;

  // combine phase: t -> (n_local = t>>3, d0 = (t&7)*8); loop heads
  int n_local = t >> 3, d0 = (t & 7) * 8;
  int tile = n_local >> 5, ql = n_local & 31;
  int qt32 = nt*2 + tile;
  #pragma unroll
  for (int h = 0; h < 4; ++h){
    int bh = b*4 + h;
    float2 mls[SPLIT];
    float m = -INFINITY;
    #pragma unroll
    for (int sp = 0; sp < SPLIT; ++sp){
      mls[sp] = ML[((size_t)((bh*SPLIT + sp)*128 + qt32))*32 + ql];
      m = fmaxf(m, mls[sp].x);
    }
    float den = 0.f, w[SPLIT];
    #pragma unroll
    for (int sp = 0; sp < SPLIT; ++sp){
      w[sp] = __builtin_amdgcn_exp2f(mls[sp].x - m);
      den += mls[sp].y * w[sp];
    }
    float inv = 1.f / den;
    float vals[8];
    #pragma unroll
    for (int j = 0; j < 8; ++j) vals[j] = 0.f;
    #pragma unroll
    for (int sp = 0; sp < SPLIT; ++sp){
      const ushort* src = Opart + ((size_t)((bh*SPLIT + sp)*128 + qt32))*2048 + (size_t)ql*64 + d0;
      uint4 a0 = *(const uint4*)src;
      float f = w[sp] * inv;
      #pragma unroll
      for (int j = 0; j < 8; ++j) vals[j] += bf2f(((const ushort*)&a0)[j]) * f;
    }
    uint32_t pk[4];
    #pragma unroll
    for (int j = 0; j < 4; ++j) pk[j] = pk2bf(vals[2*j], vals[2*j+1]);
    *(uint4*)&A[n_local][h*64 + d0] = make_uint4(pk[0], pk[1], pk[2], pk[3]);
  }
  __syncthreads();

  // GEMM phase: out[b][o][n] = W[o][ci] * A[n][ci]^T + bias + residual
  int lane = t & 63, wid = t >> 6, l15 = lane & 15, g4 = lane >> 4;
  f32x4 acc[4][2];
  #pragma unroll
  for (int mf = 0; mf < 4; ++mf)
    #pragma unroll
    for (int of = 0; of < 2; ++of) acc[mf][of] = (f32x4){0.f,0.f,0.f,0.f};

  #pragma unroll
  for (int ks = 0; ks < 8; ++ks){
    bf16x8 aa[4];
    #pragma unroll
    for (int mf = 0; mf < 4; ++mf)
      aa[mf] = *(const bf16x8*)&A[mf*16 + l15][ks*32 + g4*8];
    #pragma unroll
    for (int of = 0; of < 2; ++of){
      int o = of*128 + wid*16 + l15;
      bf16x8 bw = *(const bf16x8*)(wpb + (size_t)o*256 + ks*32 + g4*8);
      #pragma unroll
      for (int mf = 0; mf < 4; ++mf)
        acc[mf][of] = mfma16(aa[mf], bw, acc[mf][of]);
    }
  }

  #pragma unroll
  for (int of = 0; of < 2; ++of){
    int o = of*128 + wid*16 + l15;
    float bias = bproj[o];
    size_t cbase = ((size_t)b*256 + o)*4096;
    #pragma unroll
    for (int mf = 0; mf < 4; ++mf){
      int n0 = nt*64 + mf*16 + g4*4;
      f32x4 res = *(const f32x4*)(x + cbase + n0);
      f32x4 ov;
      #pragma unroll
      for (int r = 0; r < 4; ++r) ov[r] = acc[mf][of][r] + bias + res[r];
      *(f32x4*)(out + cbase + n0) = ov;
    }
  }
}

extern "C" void kernel_launch(void* const* d_in, const int* in_sizes, int n_in,
                              void* d_out, int out_size, void* d_ws, size_t ws_size,
                              hipStream_t stream) {
  const float* x     = (const float*)d_in[0];
  const float* gamma = (const float*)d_in[1];
  const float* beta  = (const float*)d_in[2];
  const float* wqkv  = (const float*)d_in[3];
  const float* bqkv  = (const float*)d_in[4];
  const float* wproj = (const float*)d_in[5];
  const float* bproj = (const float*)d_in[6];
  float* out = (float*)d_out;

  const size_t MiB = 1024*1024;
  char* ws = (char*)d_ws;
  float2* part   = (float2*)(ws + 0);            // 8 KB
  ushort* wq_b   = (ushort*)(ws + 16384);        // 384 KB
  ushort* wp_b   = (ushort*)(ws + 409600);       // 128 KB
  ushort* Qb     = (ushort*)(ws + 1*MiB);        // 4 MiB  [bh][n][d]
  ushort* Kb     = (ushort*)(ws + 5*MiB);        // 4 MiB  [bh][n][d]
  ushort* Vb     = (ushort*)(ws + 9*MiB);        // 4 MiB  [bh][d][n]
  ushort* Opart  = (ushort*)(ws + 13*MiB);       // 4*SPLIT MiB  [pw][32n][64d]

  int split = (ws_size >= 31*MiB) ? 4 : 2;
  float2* ML = (float2*)(ws + (13 + 4*(size_t)split)*MiB);  // 0.25*SPLIT MiB

  k_pg  <<<1792, 256, 0, stream>>>(wqkv, wproj, x, wq_b, wp_b, part);
  k_nqkv<<<dim3(128,2), 512, 0, stream>>>(x, gamma, beta, part, wq_b, bqkv, Qb, Kb, Vb);
  if (split == 4){
    k_attn<4><<<1024, 256, 0, stream>>>(Qb, Kb, Vb, Opart, ML);
    k_cproj<4><<<dim3(64,2), 512, 0, stream>>>(Opart, ML, wp_b, bproj, x, out);
  } else {
    k_attn<2><<<512, 256, 0, stream>>>(Qb, Kb, Vb, Opart, ML);
    k_cproj<2><<<dim3(64,2), 512, 0, stream>>>(Opart, ML, wp_b, bproj, x, out);
  }
}

// Round 7
// 153.298 us; speedup vs baseline: 1.7041x; 1.4570x over previous
//
#include <hip/hip_runtime.h>
#include <stdint.h>

#define EPS 1e-5f

typedef float f32x4 __attribute__((ext_vector_type(4)));
typedef float f32x16 __attribute__((ext_vector_type(16)));
typedef __bf16 bf16x8 __attribute__((ext_vector_type(8)));
typedef uint32_t u32x4 __attribute__((ext_vector_type(4)));

__device__ __forceinline__ ushort f2bf(float f){
  union { float f; uint32_t u; } v; v.f = f;
  uint32_t r = v.u + 0x7fffu + ((v.u >> 16) & 1u);
  return (ushort)(r >> 16);
}

__device__ __forceinline__ float bf2f(ushort u){
  union { uint32_t u; float f; } v; v.u = ((uint32_t)u) << 16;
  return v.f;
}

__device__ __forceinline__ uint32_t pk2bf(float a, float b){
  __bf16 x = (__bf16)a, y = (__bf16)b;
  return (uint32_t)__builtin_bit_cast(ushort, x) |
         ((uint32_t)__builtin_bit_cast(ushort, y) << 16);
}

__device__ __forceinline__ f32x4 mfma16(bf16x8 a, bf16x8 b, f32x4 c){
  return __builtin_amdgcn_mfma_f32_16x16x32_bf16(a, b, c, 0, 0, 0);
}
__device__ __forceinline__ f32x16 mfma32(bf16x8 a, bf16x8 b, f32x16 c){
  return __builtin_amdgcn_mfma_f32_32x32x16_bf16(a, b, c, 0, 0, 0);
}

// ---------------- fused: weight cast + groupnorm stats stage 1 ----------------
__global__ __launch_bounds__(256) void k_pg(const float* wq, const float* wp, const float* x,
                                            ushort* wqb, ushort* wpb, float2* part){
  __shared__ float red[8];
  int bid = blockIdx.x;
  if (bid < 768){
    int i = bid * 256 + threadIdx.x;
    if (i < 3*256*256) wqb[i] = f2bf(wq[i]);
    if (i < 256*256)   wpb[i] = f2bf(wp[i]);
    return;
  }
  int gb = bid - 768;
  int bg = gb >> 6, pb = gb & 63;
  const f32x4* base = (const f32x4*)(x + (size_t)bg*131072 + (size_t)pb*2048);
  float s = 0.f, ss = 0.f;
  #pragma unroll
  for (int it = 0; it < 2; ++it){
    f32x4 v = base[threadIdx.x + it*256];
    #pragma unroll
    for (int j = 0; j < 4; ++j){ s += v[j]; ss += v[j]*v[j]; }
  }
  #pragma unroll
  for (int off = 1; off < 64; off <<= 1){
    s  += __shfl_xor(s,  off);
    ss += __shfl_xor(ss, off);
  }
  int wid = threadIdx.x >> 6;
  if ((threadIdx.x & 63) == 0){ red[wid] = s; red[4 + wid] = ss; }
  __syncthreads();
  if (threadIdx.x == 0){
    part[gb] = make_float2(red[0]+red[1]+red[2]+red[3],
                           red[4]+red[5]+red[6]+red[7]);
  }
}

// ---------------- fused GN finish + normalize + QKV GEMM -> FRAGMENT layouts ----
// Qf/Kf[bh][t32:128][dsub:4][lane:64][8]   (K rows bit2<->3 permuted at write)
// Vf[bh][kb:64][dt:2][c4:4][lane:64][8]
// grid (128 nt-of-32, 2 b) x 512
__global__ __launch_bounds__(512) void k_nqkv(const float* x, const float* gamma, const float* beta,
                                              const float2* part, const ushort* wqb, const float* bqkv,
                                              ushort* Qf, ushort* Kf, ushort* Vf){
  __shared__ ushort A[32][264];      // [n][c]
  __shared__ ushort Cl[32][136];     // Q/K slabs: [n][o_local]   (272B row: 16B-aligned, slot-spread)
  __shared__ ushort Cl_T[128][40];   // V slabs:   [o_local][n]   (80B row: 16B-aligned, slot-spread)
  __shared__ float2 st[8];
  int nt = blockIdx.x, b = blockIdx.y;
  int t = threadIdx.x, lane = t & 63, wid = t >> 6;

  // finish GN stats (8 waves x 8 groups)
  {
    float2 p = part[(b*8 + wid)*64 + lane];
    float s = p.x, ss = p.y;
    #pragma unroll
    for (int off = 1; off < 64; off <<= 1){
      s  += __shfl_xor(s,  off);
      ss += __shfl_xor(ss, off);
    }
    if (lane == 0){
      const float inv = 1.f / 131072.f;
      float mean = s * inv;
      float var  = ss * inv - mean*mean;
      st[wid] = make_float2(mean, rsqrtf(var + EPS));
    }
  }
  __syncthreads();

  // normalize x-tile [256c x 32n] -> A[n][c] bf16
  {
    int c = t >> 1, nh = t & 1;
    float2 s0 = st[c >> 5];
    float g  = gamma[c] * s0.y;
    float bt = beta[c] - s0.x * g;
    const float* xr = x + ((size_t)(b*256 + c))*4096 + nt*32 + nh*16;
    #pragma unroll
    for (int j4 = 0; j4 < 4; ++j4){
      f32x4 v = *(const f32x4*)(xr + j4*4);
      #pragma unroll
      for (int e = 0; e < 4; ++e) A[nh*16 + j4*4 + e][c] = f2bf(v[e]*g + bt);
    }
  }
  __syncthreads();

  // GEMM: C[32n x 768o] = A x W^T
  int l15 = lane & 15, g4 = lane >> 4;
  f32x4 acc[6][2];
  #pragma unroll
  for (int of = 0; of < 6; ++of)
    #pragma unroll
    for (int mf = 0; mf < 2; ++mf) acc[of][mf] = (f32x4){0.f,0.f,0.f,0.f};

  #pragma unroll
  for (int ks = 0; ks < 8; ++ks){
    bf16x8 a0 = *(const bf16x8*)&A[l15][ks*32 + g4*8];
    bf16x8 a1 = *(const bf16x8*)&A[16 + l15][ks*32 + g4*8];
    #pragma unroll
    for (int of = 0; of < 6; ++of){
      int o = of*128 + wid*16 + l15;
      bf16x8 bw = *(const bf16x8*)(wqb + (size_t)o*256 + ks*32 + g4*8);
      acc[of][0] = mfma16(a0, bw, acc[of][0]);
      acc[of][1] = mfma16(a1, bw, acc[of][1]);
    }
  }

  // epilogue: per 128-o slab, stage in LDS, write fragment layouts
  #pragma unroll
  for (int of = 0; of < 6; ++of){
    __syncthreads();
    float bias = bqkv[of*128 + wid*16 + l15];
    if (of < 4){
      #pragma unroll
      for (int mf = 0; mf < 2; ++mf)
        #pragma unroll
        for (int r = 0; r < 4; ++r)
          Cl[mf*16 + g4*4 + r][wid*16 + l15] = f2bf(acc[of][mf][r] + bias);
    } else {
      #pragma unroll
      for (int mf = 0; mf < 2; ++mf)
        *(uint2*)&Cl_T[wid*16 + l15][mf*16 + g4*4] =
          make_uint2(pk2bf(acc[of][mf][0]+bias, acc[of][mf][1]+bias),
                     pk2bf(acc[of][mf][2]+bias, acc[of][mf][3]+bias));
    }
    __syncthreads();

    int hp = t >> 8;                       // head-half within slab
    int hh = (of & 1)*2 + hp;
    if (of < 4){
      int rem = t & 255, dsub = rem >> 6, ln = rem & 63, h2 = ln >> 5, p31 = ln & 31;
      int row = (of < 2) ? p31 : ((p31 & 19) | ((p31 & 4) << 1) | ((p31 & 8) >> 1));
      ushort* basep = (of < 2) ? Qf : Kf;
      uint4 v = *(const uint4*)&Cl[row][hp*64 + dsub*16 + h2*8];
      *(uint4*)(basep + ((size_t)(b*4 + hh))*262144 + nt*2048 + dsub*512 + ln*8) = v;
    } else {
      int rem = t & 255, dt = rem >> 7, r2 = rem & 127, c4h = r2 >> 5, p31 = r2 & 31;
      int c4 = (nt & 1)*2 + (c4h >> 1), h2 = c4h & 1;
      int n0 = (c4h >> 1)*16 + h2*8;
      int ln = h2*32 + p31;
      uint4 v = *(const uint4*)&Cl_T[hp*64 + dt*32 + p31][n0];
      *(uint4*)(Vf + ((size_t)(b*4 + hh))*262144 + (size_t)(nt >> 1)*4096
                   + dt*2048 + c4*512 + ln*8) = v;
    }
  }
}

// ---------------- flash attention: frag-layout streaming loads, 1-wave blocks ----
// grid 8bh * 128qt * SPLIT x 64; zero LDS, zero barriers; bh pinned per XCD.
template<int SPLIT>
__global__ __launch_bounds__(64, 3) void k_attn(const ushort* Qf, const ushort* Kf,
                                                const ushort* Vf, ushort* Opart, float2* ML){
  const float SCL2 = 0.125f * 1.44269504f;   // scale * log2(e)
  int bh = blockIdx.x & 7;
  int within = blockIdx.x >> 3;              // [0, 128*SPLIT)
  int sp = within >> 7, qt = within & 127;
  int l = threadIdx.x, l31 = l & 31, hi = l >> 5;

  const ushort* Qg = Qf + (size_t)bh*262144 + qt*2048 + l*8;
  const ushort* Kg = Kf + (size_t)bh*262144 + l*8;
  const ushort* Vg = Vf + (size_t)bh*262144 + l*8;

  bf16x8 qf[4];
  #pragma unroll
  for (int dsub = 0; dsub < 4; ++dsub)
    qf[dsub] = *(const bf16x8*)(Qg + dsub*512);

  f32x16 o[2];   // [dt]  O^T[d][q]
  #pragma unroll
  for (int dt = 0; dt < 2; ++dt)
    #pragma unroll
    for (int r = 0; r < 16; ++r) o[dt][r] = 0.f;
  float m_s = -INFINITY, l_s = 0.f;

  const int kbBeg = sp * (64 / SPLIT), kbEnd = kbBeg + 64 / SPLIT;
  for (int kb = kbBeg; kb < kbEnd; ++kb){
    // K frags (streaming: each load = 1KB contiguous)
    bf16x8 kf[2][4];
    #pragma unroll
    for (int kt = 0; kt < 2; ++kt)
      #pragma unroll
      for (int dsub = 0; dsub < 4; ++dsub)
        kf[kt][dsub] = *(const bf16x8*)(Kg + (size_t)(kb*2 + kt)*2048 + dsub*512);

    // V frags (issue early; independent of softmax)
    bf16x8 vf[2][4];
    #pragma unroll
    for (int dt = 0; dt < 2; ++dt)
      #pragma unroll
      for (int c4 = 0; c4 < 4; ++c4)
        vf[dt][c4] = *(const bf16x8*)(Vg + (size_t)kb*4096 + dt*2048 + c4*512);

    // QK: S^T[kv][q]
    f32x16 s[2];
    __builtin_amdgcn_s_setprio(1);
    #pragma unroll
    for (int kt = 0; kt < 2; ++kt){
      f32x16 acc;
      #pragma unroll
      for (int r = 0; r < 16; ++r) acc[r] = 0.f;
      #pragma unroll
      for (int dsub = 0; dsub < 4; ++dsub)
        acc = mfma32(kf[kt][dsub], qf[dsub], acc);
      s[kt] = acc;
    }
    __builtin_amdgcn_s_setprio(0);

    // softmax (q lane-local; only cross-lane partner is l^32)
    f32x16 mx = s[0];
    #pragma unroll
    for (int r = 0; r < 16; ++r) mx[r] = fmaxf(mx[r], s[1][r]);
    #pragma unroll
    for (int off = 8; off > 0; off >>= 1)
      #pragma unroll
      for (int r = 0; r < off; ++r) mx[r] = fmaxf(mx[r], mx[r + off]);
    float vm = fmaxf(mx[0], __shfl_xor(mx[0], 32)) * SCL2;

    if (__any(vm > m_s + 8.f)){
      float mn = fmaxf(m_s, vm);
      float a = __builtin_amdgcn_exp2f(m_s - mn);
      m_s = mn; l_s *= a;
      #pragma unroll
      for (int dt = 0; dt < 2; ++dt)
        #pragma unroll
        for (int r = 0; r < 16; ++r) o[dt][r] *= a;
    }
    {
      float r0 = 0.f, r1 = 0.f, r2 = 0.f, r3 = 0.f;
      #pragma unroll
      for (int kt = 0; kt < 2; ++kt)
        #pragma unroll
        for (int r = 0; r < 16; r += 4){
          float e0 = __builtin_amdgcn_exp2f(__builtin_fmaf(s[kt][r+0], SCL2, -m_s));
          float e1 = __builtin_amdgcn_exp2f(__builtin_fmaf(s[kt][r+1], SCL2, -m_s));
          float e2 = __builtin_amdgcn_exp2f(__builtin_fmaf(s[kt][r+2], SCL2, -m_s));
          float e3 = __builtin_amdgcn_exp2f(__builtin_fmaf(s[kt][r+3], SCL2, -m_s));
          s[kt][r+0] = e0; s[kt][r+1] = e1;
          s[kt][r+2] = e2; s[kt][r+3] = e3;
          r0 += e0; r1 += e1; r2 += e2; r3 += e3;
        }
      float rr = (r0 + r1) + (r2 + r3);
      rr += __shfl_xor(rr, 32);
      l_s += rr;
    }

    // P -> bf16 B-frags (pure in-lane thanks to baked K-row permutation)
    bf16x8 pf[2][2];   // [kt][ks]
    #pragma unroll
    for (int kt = 0; kt < 2; ++kt)
      #pragma unroll
      for (int ks = 0; ks < 2; ++ks){
        u32x4 w;
        #pragma unroll
        for (int c = 0; c < 4; ++c)
          w[c] = pk2bf(s[kt][8*ks + 2*c], s[kt][8*ks + 2*c + 1]);
        pf[kt][ks] = __builtin_bit_cast(bf16x8, w);
      }

    // PV: O^T[d][q]
    __builtin_amdgcn_s_setprio(1);
    #pragma unroll
    for (int dt = 0; dt < 2; ++dt)
      #pragma unroll
      for (int kt = 0; kt < 2; ++kt)
        #pragma unroll
        for (int ks = 0; ks < 2; ++ks)
          o[dt] = mfma32(vf[dt][kt*2 + ks], pf[kt][ks], o[dt]);
    __builtin_amdgcn_s_setprio(0);
  }

  // epilogue: raw partial O [pw][32n][64d] + (m,l)
  int pw = (bh*SPLIT + sp)*128 + qt;
  if (hi == 0) ML[(size_t)pw*32 + l31] = make_float2(m_s, l_s);
  ushort* dst = Opart + (size_t)pw*2048;
  #pragma unroll
  for (int dt = 0; dt < 2; ++dt)
    #pragma unroll
    for (int rq = 0; rq < 4; ++rq){
      int d0 = dt*32 + rq*8 + 4*hi;
      uint2 w = make_uint2(pk2bf(o[dt][rq*4+0], o[dt][rq*4+1]),
                           pk2bf(o[dt][rq*4+2], o[dt][rq*4+3]));
      *(uint2*)(dst + (size_t)l31*64 + d0) = w;
    }
}

// ---------------- fused combine + proj GEMM + bias + residual ----------------
// grid (64 nt, 2 b) x 512
template<int SPLIT>
__global__ __launch_bounds__(512) void k_cproj(const ushort* Opart, const float2* ML,
                                               const ushort* wpb, const float* bproj,
                                               const float* x, float* out){
  __shared__ ushort A[64][264];
  int nt = blockIdx.x, b = blockIdx.y;
  int t = threadIdx.x;

  int n_local = t >> 3, d0 = (t & 7) * 8;
  int tile = n_local >> 5, ql = n_local & 31;
  int qt32 = nt*2 + tile;
  #pragma unroll
  for (int h = 0; h < 4; ++h){
    int bh = b*4 + h;
    float2 mls[SPLIT];
    float m = -INFINITY;
    #pragma unroll
    for (int sp = 0; sp < SPLIT; ++sp){
      mls[sp] = ML[((size_t)((bh*SPLIT + sp)*128 + qt32))*32 + ql];
      m = fmaxf(m, mls[sp].x);
    }
    float den = 0.f, w[SPLIT];
    #pragma unroll
    for (int sp = 0; sp < SPLIT; ++sp){
      w[sp] = __builtin_amdgcn_exp2f(mls[sp].x - m);
      den += mls[sp].y * w[sp];
    }
    float inv = 1.f / den;
    float vals[8];
    #pragma unroll
    for (int j = 0; j < 8; ++j) vals[j] = 0.f;
    #pragma unroll
    for (int sp = 0; sp < SPLIT; ++sp){
      const ushort* src = Opart + ((size_t)((bh*SPLIT + sp)*128 + qt32))*2048 + (size_t)ql*64 + d0;
      uint4 a0 = *(const uint4*)src;
      float f = w[sp] * inv;
      #pragma unroll
      for (int j = 0; j < 8; ++j) vals[j] += bf2f(((const ushort*)&a0)[j]) * f;
    }
    uint32_t pk[4];
    #pragma unroll
    for (int j = 0; j < 4; ++j) pk[j] = pk2bf(vals[2*j], vals[2*j+1]);
    *(uint4*)&A[n_local][h*64 + d0] = make_uint4(pk[0], pk[1], pk[2], pk[3]);
  }
  __syncthreads();

  int lane = t & 63, wid = t >> 6, l15 = lane & 15, g4 = lane >> 4;
  f32x4 acc[4][2];
  #pragma unroll
  for (int mf = 0; mf < 4; ++mf)
    #pragma unroll
    for (int of = 0; of < 2; ++of) acc[mf][of] = (f32x4){0.f,0.f,0.f,0.f};

  #pragma unroll
  for (int ks = 0; ks < 8; ++ks){
    bf16x8 aa[4];
    #pragma unroll
    for (int mf = 0; mf < 4; ++mf)
      aa[mf] = *(const bf16x8*)&A[mf*16 + l15][ks*32 + g4*8];
    #pragma unroll
    for (int of = 0; of < 2; ++of){
      int o = of*128 + wid*16 + l15;
      bf16x8 bw = *(const bf16x8*)(wpb + (size_t)o*256 + ks*32 + g4*8);
      #pragma unroll
      for (int mf = 0; mf < 4; ++mf)
        acc[mf][of] = mfma16(aa[mf], bw, acc[mf][of]);
    }
  }

  #pragma unroll
  for (int of = 0; of < 2; ++of){
    int o = of*128 + wid*16 + l15;
    float bias = bproj[o];
    size_t cbase = ((size_t)b*256 + o)*4096;
    #pragma unroll
    for (int mf = 0; mf < 4; ++mf){
      int n0 = nt*64 + mf*16 + g4*4;
      f32x4 res = *(const f32x4*)(x + cbase + n0);
      f32x4 ov;
      #pragma unroll
      for (int r = 0; r < 4; ++r) ov[r] = acc[mf][of][r] + bias + res[r];
      *(f32x4*)(out + cbase + n0) = ov;
    }
  }
}

extern "C" void kernel_launch(void* const* d_in, const int* in_sizes, int n_in,
                              void* d_out, int out_size, void* d_ws, size_t ws_size,
                              hipStream_t stream) {
  const float* x     = (const float*)d_in[0];
  const float* gamma = (const float*)d_in[1];
  const float* beta  = (const float*)d_in[2];
  const float* wqkv  = (const float*)d_in[3];
  const float* bqkv  = (const float*)d_in[4];
  const float* wproj = (const float*)d_in[5];
  const float* bproj = (const float*)d_in[6];
  float* out = (float*)d_out;

  const size_t MiB = 1024*1024;
  char* ws = (char*)d_ws;
  float2* part   = (float2*)(ws + 0);            // 8 KB
  ushort* wq_b   = (ushort*)(ws + 16384);        // 384 KB
  ushort* wp_b   = (ushort*)(ws + 409600);       // 128 KB
  ushort* Qf     = (ushort*)(ws + 1*MiB);        // 4 MiB  frag layout
  ushort* Kf     = (ushort*)(ws + 5*MiB);        // 4 MiB  frag layout (rows permuted)
  ushort* Vf     = (ushort*)(ws + 9*MiB);        // 4 MiB  frag layout
  ushort* Opart  = (ushort*)(ws + 13*MiB);       // 4*SPLIT MiB  [pw][32n][64d]

  int split = (ws_size >= 31*MiB) ? 4 : 2;
  float2* ML = (float2*)(ws + (13 + 4*(size_t)split)*MiB);

  k_pg  <<<1792, 256, 0, stream>>>(wqkv, wproj, x, wq_b, wp_b, part);
  k_nqkv<<<dim3(128,2), 512, 0, stream>>>(x, gamma, beta, part, wq_b, bqkv, Qf, Kf, Vf);
  if (split == 4){
    k_attn<4><<<4096, 64, 0, stream>>>(Qf, Kf, Vf, Opart, ML);
    k_cproj<4><<<dim3(64,2), 512, 0, stream>>>(Opart, ML, wp_b, bproj, x, out);
  } else {
    k_attn<2><<<2048, 64, 0, stream>>>(Qf, Kf, Vf, Opart, ML);
    k_cproj<2><<<dim3(64,2), 512, 0, stream>>>(Opart, ML, wp_b, bproj, x, out);
  }
}